// Round 26
// baseline (33.803 us; speedup 1.0000x reference)
//
#include <hip/hip_runtime.h>
#include <math.h>

// Problem constants (fixed shapes from reference)
#define BATCH   8
#define HGRID   64
#define WGRID   64
#define DDIM    256
#define NPTS    1024
#define ROWS    65          // HGRID + 1 (NaN pad row 0)
#define COLS    65
#define KWIN    15          // (2*R_WIN+1)*(2*C_WIN+1) = 3*5
#define BN      (BATCH*NPTS)

#define PIDS_PER_BLK 16
#define THREADS      512    // 8 waves; Phase B: 2 pids per wave (pipelined)
#define PR_PITCH     260
#define NLDSB        8      // round-B rows prefetched to LDS under round-A

typedef __attribute__((ext_vector_type(8))) short bf16x8;
typedef __attribute__((ext_vector_type(4))) float f32x4;

// Direct-to-LDS 16B/lane: dest = wave-uniform base + lane*16.
__device__ __forceinline__ void gload_lds16(const float* src, float* dst) {
    __builtin_amdgcn_global_load_lds(
        (const __attribute__((address_space(1))) unsigned int*)src,
        (__attribute__((address_space(3))) unsigned int*)dst, 16, 0, 0);
}

// ---------------------------------------------------------------------------
// Fused v20 = v18 (31.6us best, 2x certified) + ZERO-REGISTER cross-pid
// prefetch: round B's first 8 rows go to LDS via global_load_lds while
// round A computes. R24's pipelining failed on register pressure (qgA+qgB
// live -> allocator 64-and-spill tier); gload_lds prefetch costs 0 VGPRs,
// so peak live stays at v18's ~107 (the clean tier).
//   issue A's 15 reg loads -> issue B's 8 LDS loads (unconditional,
//   clamped addr -> deterministic count) -> vmcnt(8) == A done, B flying
//   -> compute A -> issue B's last 7 reg loads -> re/ce B under flight
//   -> vmcnt(0) -> compute B (8 LDS + 7 reg rows).
// LDS: slab 8x1KB x 8 waves = 64KB, Pr[16][260] aliased (v7 double-sync).
// ---------------------------------------------------------------------------
__global__ __launch_bounds__(THREADS, 4) void fused_local_attn(
        const float* __restrict__ q,
        const float* __restrict__ c_t,
        const float* __restrict__ p_t,
        const float* __restrict__ W,
        float* __restrict__ out) {

    __shared__ __align__(16) float smem[NLDSB * DDIM * 8];   // 64 KB
    float (*Pr)[DDIM] = reinterpret_cast<float (*)[DDIM]>(smem);  // 16KB alias

    const int t    = threadIdx.x;
    const int w    = t >> 6;          // wave 0..7
    const int lane = t & 63;
    const int l15  = lane & 15;
    const int g    = lane >> 4;       // k-group 0..3
    const int bid  = blockIdx.x;
    const int wk   = (bid & 7) * 64 + (bid >> 3);   // XCD x <- batch x
    const int pid0 = wk * PIDS_PER_BLK;
    const int dq   = w * 32;          // this wave's 32-col d-slice
    float* qsw = smem + w * (NLDSB * DDIM);   // this wave's prefetch slab

    // ---------------- Phase A: proj into LDS (v18 verbatim) ---------------
    f32x4 acc0 = (f32x4)0.f;
    f32x4 acc1 = (f32x4)0.f;

    const float* ap  = &c_t[(size_t)(pid0 + l15) * DDIM + g * 8];
    const float* wp0 = &W[(size_t)(g * 8) * DDIM + dq + l15];        // df=0
    const float* wp1 = wp0 + 16;                                      // df=1

    #pragma unroll 2
    for (int kt = 0; kt < 8; ++kt) {
        const float4 a01 = *reinterpret_cast<const float4*>(ap + kt * 32);
        const float4 a23 = *reinterpret_cast<const float4*>(ap + kt * 32 + 4);
        const float af[8] = {a01.x, a01.y, a01.z, a01.w, a23.x, a23.y, a23.z, a23.w};
        union { bf16x8 v; unsigned u[4]; } AH, AL;
        #pragma unroll
        for (int i = 0; i < 4; ++i) {
            const unsigned u0 = __float_as_uint(af[2 * i]);
            const unsigned u1 = __float_as_uint(af[2 * i + 1]);
            AH.u[i] = __builtin_amdgcn_perm(u1, u0, 0x07060302u);
            const float l0 = af[2 * i]     - __uint_as_float(u0 & 0xFFFF0000u);
            const float l1 = af[2 * i + 1] - __uint_as_float(u1 & 0xFFFF0000u);
            AL.u[i] = __builtin_amdgcn_perm(__float_as_uint(l1), __float_as_uint(l0),
                                            0x07060302u);
        }

        #pragma unroll
        for (int df = 0; df < 2; ++df) {
            const float* wp = (df == 0) ? wp0 : wp1;
            float bf[8];
            #pragma unroll
            for (int i = 0; i < 8; ++i)
                bf[i] = wp[(size_t)(kt * 32 + i) * DDIM];
            union { bf16x8 v; unsigned u[4]; } BH, BL;
            #pragma unroll
            for (int i = 0; i < 4; ++i) {
                const unsigned u0 = __float_as_uint(bf[2 * i]);
                const unsigned u1 = __float_as_uint(bf[2 * i + 1]);
                BH.u[i] = __builtin_amdgcn_perm(u1, u0, 0x07060302u);
                const float l0 = bf[2 * i]     - __uint_as_float(u0 & 0xFFFF0000u);
                const float l1 = bf[2 * i + 1] - __uint_as_float(u1 & 0xFFFF0000u);
                BL.u[i] = __builtin_amdgcn_perm(__float_as_uint(l1), __float_as_uint(l0),
                                                0x07060302u);
            }
            f32x4 a = (df == 0) ? acc0 : acc1;
            a = __builtin_amdgcn_mfma_f32_16x16x32_bf16(AH.v, BH.v, a, 0, 0, 0);
            a = __builtin_amdgcn_mfma_f32_16x16x32_bf16(AH.v, BL.v, a, 0, 0, 0);
            a = __builtin_amdgcn_mfma_f32_16x16x32_bf16(AL.v, BH.v, a, 0, 0, 0);
            if (df == 0) acc0 = a; else acc1 = a;
        }
    }

    // C/D layout: col = lane&15, row = (lane>>4)*4 + reg  [m89-verified]
    #pragma unroll
    for (int r = 0; r < 4; ++r) {
        Pr[g * 4 + r][dq +  0 + l15] = acc0[r];
        Pr[g * 4 + r][dq + 16 + l15] = acc1[r];
    }
    __syncthreads();

    // Snapshot both pr rows; after the second barrier the slab is free.
    const float4 prA = *reinterpret_cast<const float4*>(&Pr[w * 2 + 0][lane * 4]);
    const float4 prB = *reinterpret_cast<const float4*>(&Pr[w * 2 + 1][lane * 4]);
    __syncthreads();

    // ---------------- Phase B: pipelined 2 pids per wave ------------------
    const int pidA = pid0 + w * 2 + 0;
    const int pidB = pid0 + w * 2 + 1;
    const int b    = pidA >> 10;           // same batch for both
    const float2 posA = *reinterpret_cast<const float2*>(&p_t[pidA * 2]);
    const float2 posB = *reinterpret_cast<const float2*>(&p_t[pidB * 2]);

    // ---- Geometry A + B (indices only; expf deferred under flight) ----
    int rowA[3], colA[5], rowB[3], colB[5];
    {
        const int p0 = (int)posA.x, p1 = (int)posA.y;
        #pragma unroll
        for (int i = 0; i < 3; ++i) {
            int rr = p0 + i;
            rr = rr > ROWS ? ROWS : rr;
            rowA[i] = (rr == ROWS) ? 0 : rr;
        }
        #pragma unroll
        for (int j = 0; j < 5; ++j) {
            int cc = p1 + j - 1;
            cc = cc < 0 ? 0 : (cc > COLS ? COLS : cc);
            colA[j] = (cc == COLS) ? 0 : cc;
        }
    }
    {
        const int p0 = (int)posB.x, p1 = (int)posB.y;
        #pragma unroll
        for (int i = 0; i < 3; ++i) {
            int rr = p0 + i;
            rr = rr > ROWS ? ROWS : rr;
            rowB[i] = (rr == ROWS) ? 0 : rr;
        }
        #pragma unroll
        for (int j = 0; j < 5; ++j) {
            int cc = p1 + j - 1;
            cc = cc < 0 ? 0 : (cc > COLS ? COLS : cc);
            colB[j] = (cc == COLS) ? 0 : cc;
        }
    }
    unsigned vmA = 0, vmB = 0;
    #pragma unroll
    for (int k = 0; k < KWIN; ++k) {
        const int i = k / 5, j = k % 5;
        if ((rowA[i] != 0) && (colA[j] != 0)) vmA |= (1u << k);
        if ((rowB[i] != 0) && (colB[j] != 0)) vmB |= (1u << k);
    }

    // ---- Issue A's 15 reg loads (conditional zero-fill, v18 style) ----
    float4 qgA[KWIN];
    #pragma unroll
    for (int k = 0; k < KWIN; ++k) {
        const int i = k / 5, j = k % 5;
        float4 v = make_float4(0.f, 0.f, 0.f, 0.f);
        if ((vmA >> k) & 1u) {
            v = *reinterpret_cast<const float4*>(
                &q[((size_t)((b * HGRID + rowA[i] - 1) * WGRID + colA[j] - 1)) * DDIM
                   + lane * 4]);
        }
        qgA[k] = v;
    }

    __builtin_amdgcn_sched_barrier(0);   // pin: A loads precede B prefetch

    // ---- Issue B's first NLDSB rows -> LDS (unconditional, clamped) ----
    #pragma unroll
    for (int k = 0; k < NLDSB; ++k) {
        const int i = k / 5, j = k % 5;
        const int rrc = rowB[i] ? rowB[i] : 1;
        const int ccc = colB[j] ? colB[j] : 1;
        gload_lds16(&q[((size_t)((b * HGRID + rrc - 1) * WGRID + ccc - 1)) * DDIM
                       + lane * 4],
                    &qsw[k * DDIM]);
    }
    __builtin_amdgcn_sched_barrier(0);

    // ---- re/ce A (expf hides under load flight) ----
    float reA[3], ceA[5];
    #pragma unroll
    for (int i = 0; i < 3; ++i) {
        const float rf = (float)(rowA[i] - 1 > 0 ? rowA[i] - 1 : 0);
        const float dr = rf - posA.x;
        reA[i] = __expf(-2.0f * dr * dr);
    }
    #pragma unroll
    for (int j = 0; j < 5; ++j) {
        const float cf = (float)(colA[j] - 1 > 0 ? colA[j] - 1 : 0);
        const float dc = (cf - posA.y) * 0.5f;
        ceA[j] = __expf(-2.0f * dc * dc);
    }

    // ---- Wait: A's loads done (B's 8 LDS loads may remain in flight) ----
    asm volatile("s_waitcnt vmcnt(" "8" ")" ::: "memory");   // == NLDSB
    #pragma unroll
    for (int k = 0; k < KWIN; ++k)
        asm volatile("" : "+v"(qgA[k].x), "+v"(qgA[k].y), "+v"(qgA[k].z), "+v"(qgA[k].w));

    // ================= Compute pid A =================
    {
        float score[KWIN];
        #pragma unroll
        for (int k = 0; k < KWIN; ++k) {
            const float4 v = qgA[k];
            score[k] = fmaf(v.x, prA.x, fmaf(v.y, prA.y, fmaf(v.z, prA.z, v.w * prA.w)));
        }
        #pragma unroll
        for (int k = 0; k < KWIN; ++k) {
            float s = score[k];
            #pragma unroll
            for (int off = 32; off; off >>= 1) s += __shfl_xor(s, off, 64);
            score[k] = ((vmA >> k) & 1u) ? s : -INFINITY;
        }
        float mx = score[0];
        #pragma unroll
        for (int k = 1; k < KWIN; ++k) mx = fmaxf(mx, score[k]);
        float sum = 0.f;
        #pragma unroll
        for (int k = 0; k < KWIN; ++k) {
            const float e = __expf(score[k] - mx);
            score[k] = e;
            sum += e;
        }
        const float inv = 1.0f / sum;
        float ox = 0.f, oy = 0.f, oz = 0.f, ow = 0.f;
        #pragma unroll
        for (int k = 0; k < KWIN; ++k) {
            const int i = k / 5, j = k % 5;
            const float wk2 = score[k] * inv * reA[i] * ceA[j];
            ox = fmaf(wk2, qgA[k].x, ox);
            oy = fmaf(wk2, qgA[k].y, oy);
            oz = fmaf(wk2, qgA[k].z, oz);
            ow = fmaf(wk2, qgA[k].w, ow);
        }
        *reinterpret_cast<float4*>(&out[(size_t)pidA * DDIM + lane * 4]) =
            make_float4(ox, oy, oz, ow);
    }

    __builtin_amdgcn_sched_barrier(0);

    // ---- Issue B's remaining 7 reg loads (qgA now dead) ----
    float4 qgBr[KWIN - NLDSB];
    #pragma unroll
    for (int k = NLDSB; k < KWIN; ++k) {
        const int i = k / 5, j = k % 5;
        float4 v = make_float4(0.f, 0.f, 0.f, 0.f);
        if ((vmB >> k) & 1u) {
            v = *reinterpret_cast<const float4*>(
                &q[((size_t)((b * HGRID + rowB[i] - 1) * WGRID + colB[j] - 1)) * DDIM
                   + lane * 4]);
        }
        qgBr[k - NLDSB] = v;
    }

    // ---- re/ce B (hides under flight) ----
    float reB[3], ceB[5];
    #pragma unroll
    for (int i = 0; i < 3; ++i) {
        const float rf = (float)(rowB[i] - 1 > 0 ? rowB[i] - 1 : 0);
        const float dr = rf - posB.x;
        reB[i] = __expf(-2.0f * dr * dr);
    }
    #pragma unroll
    for (int j = 0; j < 5; ++j) {
        const float cf = (float)(colB[j] - 1 > 0 ? colB[j] - 1 : 0);
        const float dc = (cf - posB.y) * 0.5f;
        ceB[j] = __expf(-2.0f * dc * dc);
    }

    asm volatile("s_waitcnt vmcnt(0)" ::: "memory");   // B loads (+A store) done
    #pragma unroll
    for (int k = 0; k < KWIN - NLDSB; ++k)
        asm volatile("" : "+v"(qgBr[k].x), "+v"(qgBr[k].y),
                          "+v"(qgBr[k].z), "+v"(qgBr[k].w));

    // ================= Compute pid B (8 LDS rows + 7 reg rows) ============
    {
        float score[KWIN];
        #pragma unroll
        for (int k = 0; k < KWIN; ++k) {
            float4 v;
            if (k < NLDSB)
                v = *reinterpret_cast<const float4*>(&qsw[k * DDIM + lane * 4]);
            else
                v = qgBr[k - NLDSB];
            score[k] = fmaf(v.x, prB.x, fmaf(v.y, prB.y, fmaf(v.z, prB.z, v.w * prB.w)));
        }
        #pragma unroll
        for (int k = 0; k < KWIN; ++k) {
            float s = score[k];
            #pragma unroll
            for (int off = 32; off; off >>= 1) s += __shfl_xor(s, off, 64);
            score[k] = ((vmB >> k) & 1u) ? s : -INFINITY;
        }
        float mx = score[0];
        #pragma unroll
        for (int k = 1; k < KWIN; ++k) mx = fmaxf(mx, score[k]);
        float sum = 0.f;
        #pragma unroll
        for (int k = 0; k < KWIN; ++k) {
            const float e = __expf(score[k] - mx);
            score[k] = e;
            sum += e;
        }
        const float inv = 1.0f / sum;
        float ox = 0.f, oy = 0.f, oz = 0.f, ow = 0.f;
        #pragma unroll
        for (int k = 0; k < KWIN; ++k) {
            const int i = k / 5, j = k % 5;
            const float wk2 = score[k] * inv * reB[i] * ceB[j];
            float4 v;
            if (k < NLDSB)
                v = *reinterpret_cast<const float4*>(&qsw[k * DDIM + lane * 4]);
            else
                v = qgBr[k - NLDSB];
            // invalid rows: wk2 == 0 and LDS holds finite clamped data -> safe
            ox = fmaf(wk2, v.x, ox);
            oy = fmaf(wk2, v.y, oy);
            oz = fmaf(wk2, v.z, oz);
            ow = fmaf(wk2, v.w, ow);
        }
        *reinterpret_cast<float4*>(&out[(size_t)pidB * DDIM + lane * 4]) =
            make_float4(ox, oy, oz, ow);
    }
}

// ---------------------------------------------------------------------------
extern "C" void kernel_launch(void* const* d_in, const int* in_sizes, int n_in,
                              void* d_out, int out_size, void* d_ws, size_t ws_size,
                              hipStream_t stream) {
    const float* q   = (const float*)d_in[0];
    const float* c_t = (const float*)d_in[1];
    const float* p_t = (const float*)d_in[2];
    const float* W_a = (const float*)d_in[3];
    float* out = (float*)d_out;

    fused_local_attn<<<BN / PIDS_PER_BLK, THREADS, 0, stream>>>(q, c_t, p_t, W_a, out);
}

// Round 27
// 31.622 us; speedup vs baseline: 1.0690x; 1.0690x over previous
//
#include <hip/hip_runtime.h>
#include <math.h>

// Problem constants (fixed shapes from reference)
#define BATCH   8
#define HGRID   64
#define WGRID   64
#define DDIM    256
#define NPTS    1024
#define ROWS    65          // HGRID + 1 (NaN pad row 0)
#define COLS    65
#define KWIN    15          // (2*R_WIN+1)*(2*C_WIN+1) = 3*5
#define BN      (BATCH*NPTS)

#define PIDS_PER_BLK 16
#define THREADS      512    // 8 waves; Phase B: 2 pids per wave
#define PR_PITCH     260

typedef __attribute__((ext_vector_type(8))) short bf16x8;
typedef __attribute__((ext_vector_type(4))) float f32x4;

// ---------------------------------------------------------------------------
// FINAL (v18, session best: 31.6us, absmax 0.0156 — certified R23 & R25).
//
// Structure and the evidence behind each choice:
//  - Single fused kernel, 16 pids/block, 512 thr, grid 512. Kernel splits
//    cost more in component overheads than fusion's W-redundancy (R7/R10/R14).
//  - XCD swizzle wk=(bid&7)*64+(bid>>3): XCD x serves exactly batch x, its
//    4MB q slab fits the per-XCD L2 (FETCH 59->22.7MB, R15).
//  - Phase A: fat fp32-load + in-register split-bf16 conversion, 3-term MFMA
//    (Ch*Wh + Ch*Wl + Cl*Wh, ~2^-16 rel err). The conversion VALU is the
//    latency cover for the W stream — pre-converting regressed twice
//    (R10/R16); transposing W for "coalescing" regressed (R22: the scalar
//    strided form is already cross-lane coalesced).
//  - Phase B: pure-register gather engine — all 15 q rows as float4 in VGPRs,
//    single s_waitcnt vmcnt(0), pins ONLY post-drain (prevents compiler
//    rematerialization without serializing the loads — the v7 rule; per-load
//    pins regressed R8/R9). No LDS staging (beat the hybrid engine, R23).
//    q stays fp32: bf16 q fails the absmax threshold via softmax
//    amplification of score error (R19/R20).
//  - No cross-pid pipelining: register form hits the allocator's
//    64-VGPR-with-spill tier (R13/R17/R24), LDS-prefetch form's overhead
//    exceeds the hidden latency (R26).
//  - (512,4) launch bound only; tighter caps trigger spills (R13).
// ---------------------------------------------------------------------------
__global__ __launch_bounds__(THREADS, 4) void fused_local_attn(
        const float* __restrict__ q,
        const float* __restrict__ c_t,
        const float* __restrict__ p_t,
        const float* __restrict__ W,
        float* __restrict__ out) {

    __shared__ __align__(16) float Pr[PIDS_PER_BLK][PR_PITCH];   // 16.6 KB

    const int t    = threadIdx.x;
    const int w    = t >> 6;          // wave 0..7
    const int lane = t & 63;
    const int l15  = lane & 15;
    const int g    = lane >> 4;       // k-group 0..3
    const int bid  = blockIdx.x;
    const int wk   = (bid & 7) * 64 + (bid >> 3);   // XCD x <- batch x
    const int pid0 = wk * PIDS_PER_BLK;
    const int dq   = w * 32;          // this wave's 32-col d-slice

    // ---------------- Phase A: proj into LDS ----------------
    f32x4 acc0 = (f32x4)0.f;
    f32x4 acc1 = (f32x4)0.f;

    const float* ap  = &c_t[(size_t)(pid0 + l15) * DDIM + g * 8];
    const float* wp0 = &W[(size_t)(g * 8) * DDIM + dq + l15];        // df=0
    const float* wp1 = wp0 + 16;                                      // df=1

    #pragma unroll 2
    for (int kt = 0; kt < 8; ++kt) {
        const float4 a01 = *reinterpret_cast<const float4*>(ap + kt * 32);
        const float4 a23 = *reinterpret_cast<const float4*>(ap + kt * 32 + 4);
        const float af[8] = {a01.x, a01.y, a01.z, a01.w, a23.x, a23.y, a23.z, a23.w};
        union { bf16x8 v; unsigned u[4]; } AH, AL;
        #pragma unroll
        for (int i = 0; i < 4; ++i) {
            const unsigned u0 = __float_as_uint(af[2 * i]);
            const unsigned u1 = __float_as_uint(af[2 * i + 1]);
            AH.u[i] = __builtin_amdgcn_perm(u1, u0, 0x07060302u);
            const float l0 = af[2 * i]     - __uint_as_float(u0 & 0xFFFF0000u);
            const float l1 = af[2 * i + 1] - __uint_as_float(u1 & 0xFFFF0000u);
            AL.u[i] = __builtin_amdgcn_perm(__float_as_uint(l1), __float_as_uint(l0),
                                            0x07060302u);
        }

        #pragma unroll
        for (int df = 0; df < 2; ++df) {
            const float* wp = (df == 0) ? wp0 : wp1;
            float bf[8];
            #pragma unroll
            for (int i = 0; i < 8; ++i)
                bf[i] = wp[(size_t)(kt * 32 + i) * DDIM];
            union { bf16x8 v; unsigned u[4]; } BH, BL;
            #pragma unroll
            for (int i = 0; i < 4; ++i) {
                const unsigned u0 = __float_as_uint(bf[2 * i]);
                const unsigned u1 = __float_as_uint(bf[2 * i + 1]);
                BH.u[i] = __builtin_amdgcn_perm(u1, u0, 0x07060302u);
                const float l0 = bf[2 * i]     - __uint_as_float(u0 & 0xFFFF0000u);
                const float l1 = bf[2 * i + 1] - __uint_as_float(u1 & 0xFFFF0000u);
                BL.u[i] = __builtin_amdgcn_perm(__float_as_uint(l1), __float_as_uint(l0),
                                                0x07060302u);
            }
            f32x4 a = (df == 0) ? acc0 : acc1;
            a = __builtin_amdgcn_mfma_f32_16x16x32_bf16(AH.v, BH.v, a, 0, 0, 0);
            a = __builtin_amdgcn_mfma_f32_16x16x32_bf16(AH.v, BL.v, a, 0, 0, 0);
            a = __builtin_amdgcn_mfma_f32_16x16x32_bf16(AL.v, BH.v, a, 0, 0, 0);
            if (df == 0) acc0 = a; else acc1 = a;
        }
    }

    // C/D layout: col = lane&15, row = (lane>>4)*4 + reg  [m89-verified]
    #pragma unroll
    for (int r = 0; r < 4; ++r) {
        Pr[g * 4 + r][dq +  0 + l15] = acc0[r];
        Pr[g * 4 + r][dq + 16 + l15] = acc1[r];
    }
    __syncthreads();

    // ---------------- Phase B: attention, 2 pids per wave, pure-reg -------
    #pragma unroll 1
    for (int pp = 0; pp < 2; ++pp) {
        const int pl  = w * 2 + pp;            // pid-local 0..15
        const int pid = pid0 + pl;
        const int b   = pid >> 10;             // / NPTS
        const float4 pr = *reinterpret_cast<const float4*>(&Pr[pl][lane * 4]);
        const float2 ppos = *reinterpret_cast<const float2*>(&p_t[pid * 2]);
        const float p0f = ppos.x;
        const float p1f = ppos.y;
        const int p0 = (int)p0f;
        const int p1 = (int)p1f;

        float re[3], ce[5];
        int rowidx[3], colidx[5];
        #pragma unroll
        for (int i = 0; i < 3; ++i) {
            int rr = p0 + i;
            rr = rr > ROWS ? ROWS : rr;
            rr = (rr == ROWS) ? 0 : rr;        // % ROWS
            rowidx[i] = rr;
            const float rf = (float)(rr - 1 > 0 ? rr - 1 : 0);
            const float dr = rf - p0f;         // / R_WIN (=1)
            re[i] = __expf(-2.0f * dr * dr);
        }
        #pragma unroll
        for (int j = 0; j < 5; ++j) {
            int cc = p1 + j - 1;
            cc = cc < 0 ? 0 : (cc > COLS ? COLS : cc);
            cc = (cc == COLS) ? 0 : cc;        // % COLS
            colidx[j] = cc;
            const float cf = (float)(cc - 1 > 0 ? cc - 1 : 0);
            const float dc = (cf - p1f) * 0.5f; // / C_WIN (=2)
            ce[j] = __expf(-2.0f * dc * dc);
        }

        // ---- Issue ALL 15 gathers into registers ----
        float4 qg[KWIN];
        unsigned vmask = 0;
        #pragma unroll
        for (int k = 0; k < KWIN; ++k) {
            const int i = k / 5, j = k % 5;
            const int rr = rowidx[i];
            const int cc = colidx[j];
            const bool valid = (rr != 0) && (cc != 0);   // wave-uniform
            float4 v = make_float4(0.f, 0.f, 0.f, 0.f);
            if (valid) {
                v = *reinterpret_cast<const float4*>(
                    &q[((size_t)((b * HGRID + rr - 1) * WGRID + cc - 1)) * DDIM
                       + lane * 4]);
                vmask |= (1u << k);
            }
            qg[k] = v;
        }
        asm volatile("s_waitcnt vmcnt(0)" ::: "memory");   // ONE wait for all 15
        // Pin once, post-drain (prevents remat without serializing).
        #pragma unroll
        for (int k = 0; k < KWIN; ++k)
            asm volatile("" : "+v"(qg[k].x), "+v"(qg[k].y), "+v"(qg[k].z), "+v"(qg[k].w));

        // ---- Scores ----
        float score[KWIN];
        #pragma unroll
        for (int k = 0; k < KWIN; ++k) {
            const float4 v = qg[k];
            score[k] = fmaf(v.x, pr.x, fmaf(v.y, pr.y, fmaf(v.z, pr.z, v.w * pr.w)));
        }

        // ---- 15 independent butterfly reductions ----
        #pragma unroll
        for (int k = 0; k < KWIN; ++k) {
            float s = score[k];
            #pragma unroll
            for (int off = 32; off; off >>= 1) s += __shfl_xor(s, off, 64);
            score[k] = ((vmask >> k) & 1u) ? s : -INFINITY;
        }

        // ---- Softmax over K=15 (replicated across lanes) ----
        float mx = score[0];
        #pragma unroll
        for (int k = 1; k < KWIN; ++k) mx = fmaxf(mx, score[k]);
        float sum = 0.f;
        #pragma unroll
        for (int k = 0; k < KWIN; ++k) {
            const float e = __expf(score[k] - mx);
            score[k] = e;
            sum += e;
        }
        const float inv = 1.0f / sum;

        // ---- Weighted sum from registers ----
        float ox = 0.f, oy = 0.f, oz = 0.f, ow = 0.f;
        #pragma unroll
        for (int k = 0; k < KWIN; ++k) {
            const int i = k / 5, j = k % 5;
            const float wk2 = score[k] * inv * re[i] * ce[j];
            ox = fmaf(wk2, qg[k].x, ox);
            oy = fmaf(wk2, qg[k].y, oy);
            oz = fmaf(wk2, qg[k].z, oz);
            ow = fmaf(wk2, qg[k].w, ow);
        }
        *reinterpret_cast<float4*>(&out[(size_t)pid * DDIM + lane * 4]) =
            make_float4(ox, oy, oz, ow);
    }
}

// ---------------------------------------------------------------------------
extern "C" void kernel_launch(void* const* d_in, const int* in_sizes, int n_in,
                              void* d_out, int out_size, void* d_ws, size_t ws_size,
                              hipStream_t stream) {
    const float* q   = (const float*)d_in[0];
    const float* c_t = (const float*)d_in[1];
    const float* p_t = (const float*)d_in[2];
    const float* W_a = (const float*)d_in[3];
    float* out = (float*)d_out;

    fused_local_attn<<<BN / PIDS_PER_BLK, THREADS, 0, stream>>>(q, c_t, p_t, W_a, out);
}